// Round 8
// baseline (164.020 us; speedup 1.0000x reference)
//
#include <hip/hip_runtime.h>
#include <hip/hip_fp16.h>

#define NSITES 262144

struct alignas(16) H8 { __half2 h[4]; };   // 8 fp16 values = 16 B
typedef __attribute__((ext_vector_type(2))) float floatx2;
typedef __attribute__((ext_vector_type(4))) unsigned int uintx4;

// Ledger (rounds 0-7):
//  * gather at unified 8MiB footprint is CLOSED at ~43.5us: 6 schedules
//    (serial/hoisted/fenced/asm-12-wide/2-pass/4-deep-pipelined) identical;
//    47.7% L2 miss = uniform-random floor (F-C)/F for 8MiB in 4MiB L2.
//  * LDS-transpose epilogue beats direct stores by ~3us (r0 vs r1, r7).
//  * r7 prep (4-site/thread) regressed ~15us: scattered 16x32B stores.
//  * fp4/fp6 G-compression closed by accuracy (g ~ N(0,64), absmax 5.5/12.24).
// This round: single-pass XCD-PARTITIONED gather. G split by batch into
// 4 x 2MiB arrays; blocks are assigned batch g=(bid&7)>>1 so with the default
// round-robin blockIdx->XCD mapping, each XCD's random footprint = 2MiB =
// half its L2. Streams (NN/Sp/out) are nt to protect residency. Perf
// heuristic only — correctness independent of the mapping.
//
// ws layout:
//   Gs [4][NSITES] uint2 fp8 e4m3, 8 B/(site,b)   (8 MiB, 4 x 2MiB)
//   Ss [4][NSITES] H8    fp16,    16 B/(site,b)   (16 MiB, 4 x 4MiB)

// wave w = batch b; lane = site. Per instr: reads 64x4B = 256B single
// segment; G store 64x8B = 512B single segment; Sp store 64x16B = 1KB.
__global__ __launch_bounds__(256) void prep_kernel(
    const float* __restrict__ In,       // [4][8][NSITES]
    const float* __restrict__ Weights,  // [8][8][16]
    const float* __restrict__ bias,     // [8][8]
    uint2* __restrict__ Gs,             // [4][NSITES]
    H8*    __restrict__ Ss)             // [4][NSITES]
{
    __shared__ float ws[8][8], wn[8][8], be[8];
    int t = threadIdx.x;
    if (t < 64) {
        int o = t >> 3, k = t & 7;
        float s0 = 0.f, s1 = 0.f;
        #pragma unroll
        for (int s = 0; s < 8; ++s) {
            s0 += Weights[s*128 + o*16 + k];
            s1 += Weights[s*128 + o*16 + 8 + k];
        }
        ws[o][k] = s0; wn[o][k] = s1;
    } else if (t < 72) {
        int o = t - 64;
        float s = 0.f;
        #pragma unroll
        for (int q = 0; q < 8; ++q) s += bias[q*8 + o];
        be[o] = s;
    }
    __syncthreads();

    int b    = t >> 6;                   // wave = batch
    int lane = t & 63;
    int site = blockIdx.x * 64 + lane;

    float x[8];
    #pragma unroll
    for (int i = 0; i < 8; ++i)
        x[i] = In[(b*8 + i) * NSITES + site];   // 256B contiguous per instr

    float g[8], sv[8];
    #pragma unroll
    for (int o = 0; o < 8; ++o) {
        float a0 = 0.f, a1 = be[o];
        #pragma unroll
        for (int i = 0; i < 8; ++i) {
            a0 = fmaf(wn[o][i], x[i], a0);
            a1 = fmaf(ws[o][i], x[i], a1);
        }
        g[o] = a0; sv[o] = a1;
    }

    unsigned int w0 = 0, w1 = 0;
    w0 = __builtin_amdgcn_cvt_pk_fp8_f32(g[0], g[1], w0, false);
    w0 = __builtin_amdgcn_cvt_pk_fp8_f32(g[2], g[3], w0, true);
    w1 = __builtin_amdgcn_cvt_pk_fp8_f32(g[4], g[5], w1, false);
    w1 = __builtin_amdgcn_cvt_pk_fp8_f32(g[6], g[7], w1, true);
    Gs[b * NSITES + site] = make_uint2(w0, w1);     // 512B contiguous per wave

    H8 hv;
    #pragma unroll
    for (int p = 0; p < 4; ++p) hv.h[p] = __floats2half2_rn(sv[2*p], sv[2*p+1]);
    Ss[b * NSITES + site] = hv;                     // 1KB contiguous per wave
}

// One thread per (site, batch-of-block). Block's batch g = (bid&7)>>1 ->
// with round-robin XCD dispatch, XCD pair {2g,2g+1} only ever gathers from
// Gs[g] (2 MiB, L2-resident). chunk c covers sites [c*256, c*256+256).
__global__ __launch_bounds__(256) void gather_kernel(
    const H8*    __restrict__ Ss,    // [4][NSITES]
    const uint2* __restrict__ Gs,    // [4][NSITES]
    const int*   __restrict__ NN,    // [13][NSITES], rows 1..12 used
    float*       __restrict__ out)   // [32][NSITES]
{
    int bid = blockIdx.x;
    int g   = (bid & 7) >> 1;                    // batch group (XCD pair)
    int c   = ((bid >> 3) << 1) | (bid & 1);     // chunk 0..1023
    int t   = threadIdx.x;                       // 256
    int n   = c * 256 + t;                       // site

    const uint2* Gb = Gs + (size_t)g * NSITES;   // 2 MiB partition

    // streaming loads (nt: don't evict the G partition)
    int m[12];
    #pragma unroll
    for (int z = 0; z < 12; ++z)
        m[z] = __builtin_nontemporal_load(&NN[(z + 1) * NSITES + n]);

    uintx4 spw = __builtin_nontemporal_load(
        (const uintx4*)(Ss + (size_t)g * NSITES) + n);
    float sp[8];
    #pragma unroll
    for (int p = 0; p < 4; ++p) {
        unsigned int wd = spw[p];
        __half2 h; __builtin_memcpy(&h, &wd, 4);
        float2 f = __half22float2(h);
        sp[2*p] = f.x; sp[2*p+1] = f.y;
    }

    const float NLOG2E = -1.44269504f;
    float acc[8], prod[8];
    #pragma unroll
    for (int k = 0; k < 8; ++k) { acc[k] = 0.f; prod[k] = 1.f; }

    #pragma unroll
    for (int z = 0; z < 12; ++z) {
        uint2 gw = Gb[m[z]];                 // 8B, cached, L2-resident partition
        float gv[8];
        floatx2 p;
        p = __builtin_amdgcn_cvt_pk_f32_fp8(gw.x, false); gv[0]=p[0]; gv[1]=p[1];
        p = __builtin_amdgcn_cvt_pk_f32_fp8(gw.x, true ); gv[2]=p[0]; gv[3]=p[1];
        p = __builtin_amdgcn_cvt_pk_f32_fp8(gw.y, false); gv[4]=p[0]; gv[5]=p[1];
        p = __builtin_amdgcn_cvt_pk_f32_fp8(gw.y, true ); gv[6]=p[0]; gv[7]=p[1];
        #pragma unroll
        for (int k = 0; k < 8; ++k) {
            float x  = sp[k] + gv[k];
            float ax = fabsf(x);
            acc[k] += fmaxf(x, 0.f);
            float e = __builtin_amdgcn_exp2f(ax * NLOG2E);  // e^-|x|
            prod[k] = fmaf(prod[k], e, prod[k]);            // Π (1+e^-|x|) ≤ 2^12
        }
    }

    // per instr (fixed k): 64 consecutive n x 4B = 256B single segment
    #pragma unroll
    for (int k = 0; k < 8; ++k) {
        float r = acc[k] + 0.69314718f * __builtin_amdgcn_logf(prod[k]);
        __builtin_nontemporal_store(r, &out[(g*8 + k) * NSITES + n]);
    }
}

extern "C" void kernel_launch(void* const* d_in, const int* in_sizes, int n_in,
                              void* d_out, int out_size, void* d_ws, size_t ws_size,
                              hipStream_t stream) {
    const float* In      = (const float*)d_in[0];
    const int*   NN      = (const int*)  d_in[1];
    const float* Weights = (const float*)d_in[2];
    const float* bias    = (const float*)d_in[3];
    float* out = (float*)d_out;

    uint2* Gs = (uint2*)d_ws;                               // 8 MiB (4 x 2MiB)
    H8*    Ss = (H8*)((char*)d_ws + (size_t)NSITES * 32);   // 16 MiB (4 x 4MiB)

    prep_kernel<<<NSITES / 64, 256, 0, stream>>>(In, Weights, bias, Gs, Ss);
    gather_kernel<<<NSITES / 64, 256, 0, stream>>>(Ss, Gs, NN, out);
}